// Round 21
// baseline (171.689 us; speedup 1.0000x reference)
//
#include <hip/hip_runtime.h>

// WaveletFeatureExtractor: db4 wavedec (5 levels, symmetric pad) -> adaptive pool 128
// -> per-level 128x128 MLP (ReLU) -> fused 640->512 MLP (ReLU).
//
// Round 21 = r20 champion with levels 1+2 FUSED via composite 22-tap filters:
// cA2[j] = sum_t CA[t] x[4j-18+t], CA[k]=sum_{2s+u=k}LO[s]LO[u] (constexpr;
// CD uses HI at level 2). r19/r20 proved the cascade is LDS-latency/barrier
// bound, not FMA-issue bound -> delete the biggest phase's LDS round trip
// (8195 cA1 writes + L2 window reads per row), one barrier, and 12.5KB LDS.
// Boundary outputs (~13/block) take an exact 2-level symfold scalar path.
// Rest identical to r20 (f16 pooled, folded pack_w, f16-dot2 mlp).

#define BATCH   2048
#define SIGLEN  16384
#define N1      8195
#define N2      4101
#define N3      2054
#define N4      1030
#define N5      518
#define POOLP   128
#define COMB    640
#define OUTD    512
#define NTHR    512

#define LW_PAIRS (5 * 128 * 128 / 2)   // 40960
#define FW_PAIRS (512 * 640 / 2)       // 163840
#define PACK_BLOCKS ((LW_PAIRS + FW_PAIRS) / 256)  // 800

#define SWZ(i) ((i) ^ ((((i) >> 5) & 7) << 2))

typedef __fp16 h2 __attribute__((ext_vector_type(2)));
typedef float  f2 __attribute__((ext_vector_type(2)));

__device__ constexpr float LO[8] = {
     0.2303778133088965f,   0.7148465705529157f,   0.6308807679298589f,
    -0.027983769416859854f, -0.18703481171909309f,  0.030841381835560764f,
     0.0328830116668852f,  -0.010597401785069032f };
__device__ constexpr float HI[8] = {
    -0.010597401785069032f, -0.0328830116668852f,   0.030841381835560764f,
     0.18703481171909309f,  -0.027983769416859854f, -0.6308807679298589f,
     0.7148465705529157f,  -0.2303778133088965f };

// Composite level-1+2 filters: offset k = 2s+u, level-2 tap s, level-1 tap u.
struct C22 { float a[22]; float d[22]; };
__device__ constexpr C22 mk_c22() {
    C22 c{};
    for (int k = 0; k < 22; ++k) { c.a[k] = 0.f; c.d[k] = 0.f; }
    for (int s = 0; s < 8; ++s)
        for (int u = 0; u < 8; ++u) {
            c.a[2 * s + u] += LO[s] * LO[u];
            c.d[2 * s + u] += HI[s] * LO[u];
        }
    return c;
}
__device__ constexpr C22 CW2 = mk_c22();

__device__ __forceinline__ int symfold(int idx, int n) {
    idx = (idx < 0) ? (-1 - idx) : idx;
    idx = (idx >= n) ? (2 * n - 1 - idx) : idx;
    return idx;
}
constexpr int cmin(int a, int b) { return a < b ? a : b; }
constexpr int cmax(int a, int b) { return a > b ? a : b; }

// Fused L1+L2: outputs cA2/cD2 [S,E) directly from global x.
// Interior (j in [8,4095], no folds): 22-tap composite on x[4j-18..4j+3].
// Boundary: exact 2-level computation with symfold.
template<int S, int E, int BDST>
__device__ __forceinline__ void dwt_l12(const float* __restrict__ xr,
                                        float* __restrict__ dstA,
                                        float* __restrict__ dstD, int tid) {
    for (int j0 = (S & ~3) + tid * 4; j0 < E; j0 += NTHR * 4) {
        if ((j0 >= 8) && (j0 <= 4092) && (j0 + 4 <= E)) {
            // x window [4j0-20, 4j0+15]: 9 aligned float4
            const float4* s4 = reinterpret_cast<const float4*>(xr + 4 * j0 - 20);
            float w[36];
#pragma unroll
            for (int q = 0; q < 9; ++q) {
                const float4 v = s4[q];
                w[4 * q] = v.x; w[4 * q + 1] = v.y; w[4 * q + 2] = v.z; w[4 * q + 3] = v.w;
            }
            float a[4], d[4];
#pragma unroll
            for (int k = 0; k < 4; ++k) {
                f2 ad = {0.f, 0.f};
#pragma unroll
                for (int t = 0; t < 22; ++t) {
                    const float v = w[4 * k + 2 + t];   // x[4(j0+k)-18+t]
                    const f2 vv = {v, v};
                    const f2 cw = {CW2.a[t], CW2.d[t]};
                    ad = __builtin_elementwise_fma(vv, cw, ad);
                }
                a[k] = ad.x; d[k] = ad.y;
            }
            const int ds = j0 - BDST;
            *reinterpret_cast<float4*>(dstA + SWZ(ds)) = make_float4(a[0], a[1], a[2], a[3]);
            *reinterpret_cast<float4*>(dstD + SWZ(ds)) = make_float4(d[0], d[1], d[2], d[3]);
        } else {
            for (int k = 0; k < 4; ++k) {
                const int j = j0 + k;
                if (j < S || j >= E) continue;
                float aa = 0.f, dd = 0.f;
#pragma unroll
                for (int s = 0; s < 8; ++s) {
                    const int i = symfold(2 * j - 6 + s, N1);
                    float l1 = 0.f;
#pragma unroll
                    for (int u = 0; u < 8; ++u) {
                        l1 = fmaf(xr[symfold(2 * i - 6 + u, SIGLEN)], LO[u], l1);
                    }
                    aa = fmaf(l1, LO[s], aa);
                    dd = fmaf(l1, HI[s], dd);
                }
                dstA[SWZ(j - BDST)] = aa;
                dstD[SWZ(j - BDST)] = dd;
            }
        }
    }
}

template<int SS, int SE, int BSRC, int NSRC, int S, int E, int BDST>
__device__ __forceinline__ void dwt_chunk(const float* __restrict__ src,
                                          float* __restrict__ dstA,
                                          float* __restrict__ dstD, int tid) {
    for (int j0 = (S & ~3) + tid * 4; j0 < E; j0 += NTHR * 4) {
        const int rb = 2 * j0 - 8;
        if ((rb >= SS) && (2 * j0 + 7 <= SE - 1) && (j0 + 4 <= E)) {
            const int lrb = rb - BSRC;
            const float4 v0 = *reinterpret_cast<const float4*>(src + SWZ(lrb));
            const float4 v1 = *reinterpret_cast<const float4*>(src + SWZ(lrb + 4));
            const float4 v2 = *reinterpret_cast<const float4*>(src + SWZ(lrb + 8));
            const float4 v3 = *reinterpret_cast<const float4*>(src + SWZ(lrb + 12));
            float w[16];
            w[0]=v0.x;  w[1]=v0.y;  w[2]=v0.z;  w[3]=v0.w;
            w[4]=v1.x;  w[5]=v1.y;  w[6]=v1.z;  w[7]=v1.w;
            w[8]=v2.x;  w[9]=v2.y;  w[10]=v2.z; w[11]=v2.w;
            w[12]=v3.x; w[13]=v3.y; w[14]=v3.z; w[15]=v3.w;
            float a[4], d[4];
#pragma unroll
            for (int k = 0; k < 4; ++k) {
                f2 ad = {0.f, 0.f};
#pragma unroll
                for (int t = 0; t < 8; ++t) {
                    const float v = w[2 + 2 * k + t];
                    const f2 vv = {v, v};
                    const f2 lh = {LO[t], HI[t]};
                    ad = __builtin_elementwise_fma(vv, lh, ad);
                }
                a[k] = ad.x; d[k] = ad.y;
            }
            const int ds = j0 - BDST;
            *reinterpret_cast<float4*>(dstA + SWZ(ds)) = make_float4(a[0], a[1], a[2], a[3]);
            *reinterpret_cast<float4*>(dstD + SWZ(ds)) = make_float4(d[0], d[1], d[2], d[3]);
        } else {
            for (int k = 0; k < 4; ++k) {
                const int j = j0 + k;
                if (j < S || j >= E) continue;
                float aa = 0.f, dd = 0.f;
#pragma unroll
                for (int t = 0; t < 8; ++t) {
                    const int idx = symfold(2 * j - 6 + t, NSRC);
                    const float v = src[SWZ(idx - BSRC)];
                    aa = fmaf(v, LO[t], aa);
                    dd = fmaf(v, HI[t], dd);
                }
                dstA[SWZ(j - BDST)] = aa;
                dstD[SWZ(j - BDST)] = dd;
            }
        }
    }
}

// Pool 64 owned buckets; lane 0 writes the mean as f16 (RTE).
template<int N, int BASE, int P0>
__device__ __forceinline__ void pool64(const float* __restrict__ buf,
                                       __fp16* __restrict__ dst, int tid) {
    const int p = P0 + (tid >> 3), sub = tid & 7;
    const int s = (p * N) >> 7;
    const int e = ((p + 1) * N + 127) >> 7;
    float acc = 0.f;
    for (int t = s + sub; t < e; t += 8) acc += buf[SWZ(t - BASE)];
    acc += __shfl_xor(acc, 1);
    acc += __shfl_xor(acc, 2);
    acc += __shfl_xor(acc, 4);
    if (sub == 0) dst[p] = (__fp16)(acc / (float)(e - s));
}

template<int B>
__device__ __forceinline__ void dwt_body(const float* __restrict__ xr,
                                         __fp16* __restrict__ pr,
                                         float* __restrict__ A, float* __restrict__ Bb,
                                         float* __restrict__ D1, float* __restrict__ D2,
                                         int tid) {
    constexpr int p0 = B * 64;
    constexpr int sP5 = (p0 * N5) >> 7, eP5 = ((p0 + 64) * N5 + 127) >> 7;
    constexpr int sP4 = (p0 * N4) >> 7, eP4 = ((p0 + 64) * N4 + 127) >> 7;
    constexpr int sP3 = (p0 * N3) >> 7, eP3 = ((p0 + 64) * N3 + 127) >> 7;
    constexpr int sP2 = (p0 * N2) >> 7, eP2 = ((p0 + 64) * N2 + 127) >> 7;
    constexpr int s5 = sP5, e5 = cmin(eP5, N5);
    constexpr int s4 = cmax(cmin(sP4, 2 * s5 - 6), 0);
    constexpr int e4 = cmin(cmax(eP4, 2 * e5), N4);
    constexpr int s3 = cmax(cmin(sP3, 2 * s4 - 6), 0);
    constexpr int e3 = cmin(cmax(eP3, 2 * e4), N3);
    constexpr int s2 = cmax(cmin(sP2, 2 * s3 - 6), 0);
    constexpr int e2 = cmin(cmax(eP2, 2 * e3), N2);
    constexpr int b2 = (s2 & ~3) - 8, b3 = (s3 & ~3) - 8;
    constexpr int b4 = (s4 & ~3) - 8, b5 = (s5 & ~3) - 8;

    // P0: fused L1+L2 from global x -> Bb(cA2), D1(cD2)
    dwt_l12<s2, e2, b2>(xr, Bb, D1, tid);
    __syncthreads();
    // P1: L3: Bb -> A(cA3), D2(cD3)   || pool cD2 -> slot 4
    dwt_chunk<s2, e2, b2, N2, s3, e3, b3>(Bb, A, D2, tid);
    pool64<N2, b2, p0>(D1, pr + 4 * POOLP, tid);
    __syncthreads();
    // P2: L4: A -> Bb(cA4), D1(cD4)   || pool cD3 -> slot 3
    dwt_chunk<s3, e3, b3, N3, s4, e4, b4>(A, Bb, D1, tid);
    pool64<N3, b3, p0>(D2, pr + 3 * POOLP, tid);
    __syncthreads();
    // P3: L5: Bb -> A(cA5), D2(cD5)   || pool cD4 -> slot 2
    dwt_chunk<s4, e4, b4, N4, s5, e5, b5>(Bb, A, D2, tid);
    pool64<N4, b4, p0>(D1, pr + 2 * POOLP, tid);
    __syncthreads();
    // P4: pool cA5 -> slot 0, cD5 -> slot 1
    pool64<N5, b5, p0>(A,  pr + 0 * POOLP, tid);
    pool64<N5, b5, p0>(D2, pr + 1 * POOLP, tid);
}

__global__ __launch_bounds__(NTHR, 4) void dwt_pool_kernel(const float* __restrict__ x,
                                                           __fp16* __restrict__ pooled,
                                                           const float* __restrict__ lw,
                                                           const float* __restrict__ fw,
                                                           h2* __restrict__ lwh,   // null -> skip pack
                                                           h2* __restrict__ fwh) {
    __shared__ __align__(16) float A[1088];    // cA3 / cA5 chunks
    __shared__ __align__(16) float Bb[2144];   // cA2 / cA4 chunks
    __shared__ __align__(16) float D1[2144];   // cD2 / cD4 chunks
    __shared__ __align__(16) float D2[1088];   // cD3 / cD5 chunks
    const int tid = threadIdx.x;

    // folded weight packing (independent of dwt; mlp launches after this kernel)
    if (lwh != nullptr && blockIdx.x < PACK_BLOCKS && tid < 256) {
        const int i = blockIdx.x * 256 + tid;
        if (i < LW_PAIRS) {
            const float2 v = reinterpret_cast<const float2*>(lw)[i];
            lwh[i] = __builtin_amdgcn_cvt_pkrtz(v.x, v.y);
        } else {
            const float2 v = reinterpret_cast<const float2*>(fw)[i - LW_PAIRS];
            fwh[i - LW_PAIRS] = __builtin_amdgcn_cvt_pkrtz(v.x, v.y);
        }
    }

    const int row = blockIdx.x >> 1;
    const float* __restrict__ xr = x + (size_t)row * SIGLEN;
    __fp16* __restrict__ pr = pooled + (size_t)row * COMB;
    if (blockIdx.x & 1) dwt_body<1>(xr, pr, A, Bb, D1, D2, tid);
    else                dwt_body<0>(xr, pr, A, Bb, D1, D2, tid);
}

// ---------------- MLP (r18: f16 pooled input, pre-packed f16 weights) ----------------

__global__ __launch_bounds__(1024, 4) void mlp_kernel(const __fp16* __restrict__ pooled,
                                                      const h2* __restrict__ lwh,
                                                      const float* __restrict__ lb,
                                                      const h2* __restrict__ fwh,
                                                      const float* __restrict__ fb,
                                                      float* __restrict__ out) {
    __shared__ h2 sph[8][COMB / 2];
    __shared__ h2 sch[8][COMB / 2];
    const int tid = threadIdx.x;
    const int r0 = blockIdx.x * 8;

    const h2* __restrict__ srcp = reinterpret_cast<const h2*>(pooled + (size_t)r0 * COMB);
    for (int i = tid; i < 8 * (COMB / 2); i += 1024) {
        (&sph[0][0])[i] = srcp[i];
    }
    __syncthreads();

    for (int idx = tid; idx < COMB * 2; idx += 1024) {
        const int c = idx >> 1, rh = (idx & 1) * 4;
        const h2* __restrict__ w = lwh + (size_t)c * 64;
        const int lb2 = (c >> 7) * 64;
        const float bias = lb[c];
        float acc[4] = {bias, bias, bias, bias};
        for (int t2 = 0; t2 < 64; t2 += 4) {
            const float4 wraw = *reinterpret_cast<const float4*>(w + t2);
            const h2 w0 = __builtin_bit_cast(h2, wraw.x);
            const h2 w1 = __builtin_bit_cast(h2, wraw.y);
            const h2 w2 = __builtin_bit_cast(h2, wraw.z);
            const h2 w3 = __builtin_bit_cast(h2, wraw.w);
#pragma unroll
            for (int r = 0; r < 4; ++r) {
                const float4 praw = *reinterpret_cast<const float4*>(&sph[rh + r][lb2 + t2]);
                acc[r] = __builtin_amdgcn_fdot2(__builtin_bit_cast(h2, praw.x), w0, acc[r], false);
                acc[r] = __builtin_amdgcn_fdot2(__builtin_bit_cast(h2, praw.y), w1, acc[r], false);
                acc[r] = __builtin_amdgcn_fdot2(__builtin_bit_cast(h2, praw.z), w2, acc[r], false);
                acc[r] = __builtin_amdgcn_fdot2(__builtin_bit_cast(h2, praw.w), w3, acc[r], false);
            }
        }
        __fp16* __restrict__ schf = reinterpret_cast<__fp16*>(&sch[0][0]);
#pragma unroll
        for (int r = 0; r < 4; ++r) schf[(rh + r) * COMB + c] = (__fp16)fmaxf(acc[r], 0.f);
    }
    __syncthreads();

    {
        const int c = tid >> 1, rh = (tid & 1) * 4;
        const h2* __restrict__ w = fwh + (size_t)c * (COMB / 2);
        const float bias = fb[c];
        float acc[4] = {bias, bias, bias, bias};
        for (int t2 = 0; t2 < COMB / 2; t2 += 4) {
            const float4 wraw = *reinterpret_cast<const float4*>(w + t2);
            const h2 w0 = __builtin_bit_cast(h2, wraw.x);
            const h2 w1 = __builtin_bit_cast(h2, wraw.y);
            const h2 w2 = __builtin_bit_cast(h2, wraw.z);
            const h2 w3 = __builtin_bit_cast(h2, wraw.w);
#pragma unroll
            for (int r = 0; r < 4; ++r) {
                const float4 craw = *reinterpret_cast<const float4*>(&sch[rh + r][t2]);
                acc[r] = __builtin_amdgcn_fdot2(__builtin_bit_cast(h2, craw.x), w0, acc[r], false);
                acc[r] = __builtin_amdgcn_fdot2(__builtin_bit_cast(h2, craw.y), w1, acc[r], false);
                acc[r] = __builtin_amdgcn_fdot2(__builtin_bit_cast(h2, craw.z), w2, acc[r], false);
                acc[r] = __builtin_amdgcn_fdot2(__builtin_bit_cast(h2, craw.w), w3, acc[r], false);
            }
        }
#pragma unroll
        for (int r = 0; r < 4; ++r) {
            out[(size_t)(r0 + rh + r) * OUTD + c] = fmaxf(acc[r], 0.f);
        }
    }
}

// Fallback mlp: in-kernel weight cvt (used if d_ws lacks packed-weight space)
__global__ __launch_bounds__(512) void mlp_kernel_fb(const __fp16* __restrict__ pooled,
                                                     const float* __restrict__ lw,
                                                     const float* __restrict__ lb,
                                                     const float* __restrict__ fw,
                                                     const float* __restrict__ fb,
                                                     float* __restrict__ out) {
    __shared__ h2 sph[8][COMB / 2];
    __shared__ h2 sch[8][COMB / 2];
    const int tid = threadIdx.x;
    const int r0 = blockIdx.x * 8;
    const h2* __restrict__ srcp = reinterpret_cast<const h2*>(pooled + (size_t)r0 * COMB);
    for (int i = tid; i < 8 * (COMB / 2); i += 512) {
        (&sph[0][0])[i] = srcp[i];
    }
    __syncthreads();
    for (int c = tid; c < COMB; c += 512) {
        const float* __restrict__ w = lw + (size_t)c * POOLP;
        const int lb2 = (c >> 7) * (POOLP / 2);
        const float bias = lb[c];
        float acc[8];
#pragma unroll
        for (int r = 0; r < 8; ++r) acc[r] = bias;
        for (int t2 = 0; t2 < POOLP / 2; t2 += 4) {
            const float4 wa = *reinterpret_cast<const float4*>(w + t2 * 2);
            const float4 wb = *reinterpret_cast<const float4*>(w + t2 * 2 + 4);
            const h2 w0 = __builtin_amdgcn_cvt_pkrtz(wa.x, wa.y);
            const h2 w1 = __builtin_amdgcn_cvt_pkrtz(wa.z, wa.w);
            const h2 w2 = __builtin_amdgcn_cvt_pkrtz(wb.x, wb.y);
            const h2 w3 = __builtin_amdgcn_cvt_pkrtz(wb.z, wb.w);
#pragma unroll
            for (int r = 0; r < 8; ++r) {
                const float4 raw = *reinterpret_cast<const float4*>(&sph[r][lb2 + t2]);
                acc[r] = __builtin_amdgcn_fdot2(__builtin_bit_cast(h2, raw.x), w0, acc[r], false);
                acc[r] = __builtin_amdgcn_fdot2(__builtin_bit_cast(h2, raw.y), w1, acc[r], false);
                acc[r] = __builtin_amdgcn_fdot2(__builtin_bit_cast(h2, raw.z), w2, acc[r], false);
                acc[r] = __builtin_amdgcn_fdot2(__builtin_bit_cast(h2, raw.w), w3, acc[r], false);
            }
        }
        __fp16* __restrict__ schf = reinterpret_cast<__fp16*>(&sch[0][0]);
#pragma unroll
        for (int r = 0; r < 8; ++r) schf[r * COMB + c] = (__fp16)fmaxf(acc[r], 0.f);
    }
    __syncthreads();
    {
        const int j = tid;
        const float* __restrict__ w = fw + (size_t)j * COMB;
        const float bias = fb[j];
        float acc[8];
#pragma unroll
        for (int r = 0; r < 8; ++r) acc[r] = bias;
        for (int t2 = 0; t2 < COMB / 2; t2 += 4) {
            const float4 wa = *reinterpret_cast<const float4*>(w + t2 * 2);
            const float4 wb = *reinterpret_cast<const float4*>(w + t2 * 2 + 4);
            const h2 w0 = __builtin_amdgcn_cvt_pkrtz(wa.x, wa.y);
            const h2 w1 = __builtin_amdgcn_cvt_pkrtz(wa.z, wa.w);
            const h2 w2 = __builtin_amdgcn_cvt_pkrtz(wb.x, wb.y);
            const h2 w3 = __builtin_amdgcn_cvt_pkrtz(wb.z, wb.w);
#pragma unroll
            for (int r = 0; r < 8; ++r) {
                const float4 raw = *reinterpret_cast<const float4*>(&sch[r][t2]);
                acc[r] = __builtin_amdgcn_fdot2(__builtin_bit_cast(h2, raw.x), w0, acc[r], false);
                acc[r] = __builtin_amdgcn_fdot2(__builtin_bit_cast(h2, raw.y), w1, acc[r], false);
                acc[r] = __builtin_amdgcn_fdot2(__builtin_bit_cast(h2, raw.z), w2, acc[r], false);
                acc[r] = __builtin_amdgcn_fdot2(__builtin_bit_cast(h2, raw.w), w3, acc[r], false);
            }
        }
#pragma unroll
        for (int r = 0; r < 8; ++r) {
            out[(size_t)(r0 + r) * OUTD + j] = fmaxf(acc[r], 0.f);
        }
    }
}

extern "C" void kernel_launch(void* const* d_in, const int* in_sizes, int n_in,
                              void* d_out, int out_size, void* d_ws, size_t ws_size,
                              hipStream_t stream) {
    const float* x  = (const float*)d_in[0];
    const float* lw = (const float*)d_in[1];
    const float* lb = (const float*)d_in[2];
    const float* fw = (const float*)d_in[3];
    const float* fb = (const float*)d_in[4];
    float* out = (float*)d_out;

    char* base = (char*)d_ws;
    const size_t POOLED_B = (size_t)BATCH * COMB * 2;            // f16, 2,621,440
    const size_t LWH_B    = (size_t)LW_PAIRS * 4;                // 163,840
    const size_t FWH_B    = (size_t)FW_PAIRS * 4;                // 655,360

    __fp16* pooled = (__fp16*)base;
    h2* lwh = (h2*)(base + POOLED_B);
    h2* fwh = (h2*)(base + POOLED_B + LWH_B);

    const bool packed = (ws_size >= POOLED_B + LWH_B + FWH_B);

    dwt_pool_kernel<<<BATCH * 2, NTHR, 0, stream>>>(x, pooled, lw, fw,
                                                    packed ? lwh : nullptr,
                                                    packed ? fwh : nullptr);

    if (packed) {
        mlp_kernel<<<BATCH / 8, 1024, 0, stream>>>(pooled, lwh, lb, fwh, fb, out);
    } else {
        mlp_kernel_fb<<<BATCH / 8, 512, 0, stream>>>(pooled, lw, lb, fw, fb, out);
    }
}

// Round 22
// 88.432 us; speedup vs baseline: 1.9415x; 1.9415x over previous
//
#include <hip/hip_runtime.h>

// WaveletFeatureExtractor: db4 wavedec (5 levels, symmetric pad) -> adaptive pool 128
// -> per-level 128x128 MLP (ReLU) -> fused 640->512 MLP (ReLU).
//
// Round 22 = FINAL: byte-for-byte revert to the r20 champion (87.98 us).
// Ledger: cascade dwt (2 blocks/row, constexpr geometry, XOR-swizzled LDS,
// lb(512,4)) 76 us + f16 pooled (RTE, error-free vs the mlp's RTZ round-trip)
// + folded weight packing + f16-dot2 mlp. r21's fused-L12 regressed (155 us:
// 64B-stride uncoalesced global windows + VGPR=32 serialized loads); r13-r17
// banded arc never beat the cascade; r19/r20 proved latency-structure-bound
// (pk_fma flat at 48% VALUBusy, occupancy at the 32-wave cap).

#define BATCH   2048
#define SIGLEN  16384
#define N1      8195
#define N2      4101
#define N3      2054
#define N4      1030
#define N5      518
#define POOLP   128
#define COMB    640
#define OUTD    512
#define NTHR    512

#define LW_PAIRS (5 * 128 * 128 / 2)   // 40960
#define FW_PAIRS (512 * 640 / 2)       // 163840
#define PACK_BLOCKS ((LW_PAIRS + FW_PAIRS) / 256)  // 800

#define SWZ(i) ((i) ^ ((((i) >> 5) & 7) << 2))

typedef __fp16 h2 __attribute__((ext_vector_type(2)));
typedef float  f2 __attribute__((ext_vector_type(2)));

__device__ constexpr float LO[8] = {
     0.2303778133088965f,   0.7148465705529157f,   0.6308807679298589f,
    -0.027983769416859854f, -0.18703481171909309f,  0.030841381835560764f,
     0.0328830116668852f,  -0.010597401785069032f };
__device__ constexpr float HI[8] = {
    -0.010597401785069032f, -0.0328830116668852f,   0.030841381835560764f,
     0.18703481171909309f,  -0.027983769416859854f, -0.6308807679298589f,
     0.7148465705529157f,  -0.2303778133088965f };

__device__ __forceinline__ int symfold(int idx, int n) {
    idx = (idx < 0) ? (-1 - idx) : idx;
    idx = (idx >= n) ? (2 * n - 1 - idx) : idx;
    return idx;
}
constexpr int cmin(int a, int b) { return a < b ? a : b; }
constexpr int cmax(int a, int b) { return a > b ? a : b; }

template<int SS, int SE, int BSRC, int NSRC, int S, int E, int BDST>
__device__ __forceinline__ void dwt_chunk(const float* __restrict__ src,
                                          float* __restrict__ dstA,
                                          float* __restrict__ dstD, int tid) {
    for (int j0 = (S & ~3) + tid * 4; j0 < E; j0 += NTHR * 4) {
        const int rb = 2 * j0 - 8;
        if ((rb >= SS) && (2 * j0 + 7 <= SE - 1) && (j0 + 4 <= E)) {
            const int lrb = rb - BSRC;
            const float4 v0 = *reinterpret_cast<const float4*>(src + SWZ(lrb));
            const float4 v1 = *reinterpret_cast<const float4*>(src + SWZ(lrb + 4));
            const float4 v2 = *reinterpret_cast<const float4*>(src + SWZ(lrb + 8));
            const float4 v3 = *reinterpret_cast<const float4*>(src + SWZ(lrb + 12));
            float w[16];
            w[0]=v0.x;  w[1]=v0.y;  w[2]=v0.z;  w[3]=v0.w;
            w[4]=v1.x;  w[5]=v1.y;  w[6]=v1.z;  w[7]=v1.w;
            w[8]=v2.x;  w[9]=v2.y;  w[10]=v2.z; w[11]=v2.w;
            w[12]=v3.x; w[13]=v3.y; w[14]=v3.z; w[15]=v3.w;
            float a[4], d[4];
#pragma unroll
            for (int k = 0; k < 4; ++k) {
                f2 ad = {0.f, 0.f};
#pragma unroll
                for (int t = 0; t < 8; ++t) {
                    const float v = w[2 + 2 * k + t];
                    const f2 vv = {v, v};
                    const f2 lh = {LO[t], HI[t]};
                    ad = __builtin_elementwise_fma(vv, lh, ad);   // v_pk_fma_f32
                }
                a[k] = ad.x; d[k] = ad.y;
            }
            const int ds = j0 - BDST;
            *reinterpret_cast<float4*>(dstA + SWZ(ds)) = make_float4(a[0], a[1], a[2], a[3]);
            *reinterpret_cast<float4*>(dstD + SWZ(ds)) = make_float4(d[0], d[1], d[2], d[3]);
        } else {
            for (int k = 0; k < 4; ++k) {
                const int j = j0 + k;
                if (j < S || j >= E) continue;
                float aa = 0.f, dd = 0.f;
#pragma unroll
                for (int t = 0; t < 8; ++t) {
                    const int idx = symfold(2 * j - 6 + t, NSRC);
                    const float v = src[SWZ(idx - BSRC)];
                    aa = fmaf(v, LO[t], aa);
                    dd = fmaf(v, HI[t], dd);
                }
                dstA[SWZ(j - BDST)] = aa;
                dstD[SWZ(j - BDST)] = dd;
            }
        }
    }
}

template<int S, int E, int BDST>
__device__ __forceinline__ void dwt_l1(const float* __restrict__ xr,
                                       float* __restrict__ dstA, int tid) {
    for (int j0 = (S & ~3) + tid * 4; j0 < E; j0 += NTHR * 4) {
        const int rb = 2 * j0 - 8;
        if ((rb >= 0) && (2 * j0 + 7 <= SIGLEN - 1) && (j0 + 4 <= E)) {
            const float4* s4 = reinterpret_cast<const float4*>(xr + rb);
            const float4 v0 = s4[0], v1 = s4[1], v2 = s4[2], v3 = s4[3];
            float w[16];
            w[0]=v0.x;  w[1]=v0.y;  w[2]=v0.z;  w[3]=v0.w;
            w[4]=v1.x;  w[5]=v1.y;  w[6]=v1.z;  w[7]=v1.w;
            w[8]=v2.x;  w[9]=v2.y;  w[10]=v2.z; w[11]=v2.w;
            w[12]=v3.x; w[13]=v3.y; w[14]=v3.z; w[15]=v3.w;
            f2 a01 = {0.f, 0.f}, a23 = {0.f, 0.f};
#pragma unroll
            for (int t = 0; t < 8; ++t) {
                const f2 p01 = {w[2 + t], w[4 + t]};
                const f2 p23 = {w[6 + t], w[8 + t]};
                const f2 lt  = {LO[t], LO[t]};
                a01 = __builtin_elementwise_fma(p01, lt, a01);
                a23 = __builtin_elementwise_fma(p23, lt, a23);
            }
            *reinterpret_cast<float4*>(dstA + SWZ(j0 - BDST)) =
                make_float4(a01.x, a01.y, a23.x, a23.y);
        } else {
            for (int k = 0; k < 4; ++k) {
                const int j = j0 + k;
                if (j < S || j >= E) continue;
                float aa = 0.f;
#pragma unroll
                for (int t = 0; t < 8; ++t) {
                    const int idx = symfold(2 * j - 6 + t, SIGLEN);
                    aa = fmaf(xr[idx], LO[t], aa);
                }
                dstA[SWZ(j - BDST)] = aa;
            }
        }
    }
}

// Pool 64 owned buckets; lane 0 writes the mean as f16 (RTE).
template<int N, int BASE, int P0>
__device__ __forceinline__ void pool64(const float* __restrict__ buf,
                                       __fp16* __restrict__ dst, int tid) {
    const int p = P0 + (tid >> 3), sub = tid & 7;
    const int s = (p * N) >> 7;
    const int e = ((p + 1) * N + 127) >> 7;
    float acc = 0.f;
    for (int t = s + sub; t < e; t += 8) acc += buf[SWZ(t - BASE)];
    acc += __shfl_xor(acc, 1);
    acc += __shfl_xor(acc, 2);
    acc += __shfl_xor(acc, 4);
    if (sub == 0) dst[p] = (__fp16)(acc / (float)(e - s));
}

template<int B>
__device__ __forceinline__ void dwt_body(const float* __restrict__ xr,
                                         __fp16* __restrict__ pr,
                                         float* __restrict__ A, float* __restrict__ Bb,
                                         float* __restrict__ D1, float* __restrict__ D2,
                                         int tid) {
    constexpr int p0 = B * 64;
    constexpr int sP5 = (p0 * N5) >> 7, eP5 = ((p0 + 64) * N5 + 127) >> 7;
    constexpr int sP4 = (p0 * N4) >> 7, eP4 = ((p0 + 64) * N4 + 127) >> 7;
    constexpr int sP3 = (p0 * N3) >> 7, eP3 = ((p0 + 64) * N3 + 127) >> 7;
    constexpr int sP2 = (p0 * N2) >> 7, eP2 = ((p0 + 64) * N2 + 127) >> 7;
    constexpr int s5 = sP5, e5 = cmin(eP5, N5);
    constexpr int s4 = cmax(cmin(sP4, 2 * s5 - 6), 0);
    constexpr int e4 = cmin(cmax(eP4, 2 * e5), N4);
    constexpr int s3 = cmax(cmin(sP3, 2 * s4 - 6), 0);
    constexpr int e3 = cmin(cmax(eP3, 2 * e4), N3);
    constexpr int s2 = cmax(cmin(sP2, 2 * s3 - 6), 0);
    constexpr int e2 = cmin(cmax(eP2, 2 * e3), N2);
    constexpr int s1 = cmax(2 * s2 - 6, 0);
    constexpr int e1 = cmin(2 * e2, N1);
    constexpr int b1 = (s1 & ~3) - 8, b2 = (s2 & ~3) - 8, b3 = (s3 & ~3) - 8;
    constexpr int b4 = (s4 & ~3) - 8, b5 = (s5 & ~3) - 8;

    dwt_l1<s1, e1, b1>(xr, A, tid);
    __syncthreads();
    dwt_chunk<s1, e1, b1, N1, s2, e2, b2>(A, Bb, D1, tid);
    __syncthreads();
    dwt_chunk<s2, e2, b2, N2, s3, e3, b3>(Bb, A, D2, tid);
    pool64<N2, b2, p0>(D1, pr + 4 * POOLP, tid);
    __syncthreads();
    dwt_chunk<s3, e3, b3, N3, s4, e4, b4>(A, Bb, D1, tid);
    pool64<N3, b3, p0>(D2, pr + 3 * POOLP, tid);
    __syncthreads();
    dwt_chunk<s4, e4, b4, N4, s5, e5, b5>(Bb, A, D2, tid);
    pool64<N4, b4, p0>(D1, pr + 2 * POOLP, tid);
    __syncthreads();
    pool64<N5, b5, p0>(A,  pr + 0 * POOLP, tid);
    pool64<N5, b5, p0>(D2, pr + 1 * POOLP, tid);
}

__global__ __launch_bounds__(NTHR, 4) void dwt_pool_kernel(const float* __restrict__ x,
                                                           __fp16* __restrict__ pooled,
                                                           const float* __restrict__ lw,
                                                           const float* __restrict__ fw,
                                                           h2* __restrict__ lwh,   // null -> skip pack
                                                           h2* __restrict__ fwh) {
    __shared__ __align__(16) float A[4192];
    __shared__ __align__(16) float Bb[2144];
    __shared__ __align__(16) float D1[2144];
    __shared__ __align__(16) float D2[1088];
    const int tid = threadIdx.x;

    // folded weight packing: first 800 blocks convert 256 f32 pairs each
    // (independent of the dwt below; mlp launches after this kernel completes)
    if (lwh != nullptr && blockIdx.x < PACK_BLOCKS && tid < 256) {
        const int i = blockIdx.x * 256 + tid;
        if (i < LW_PAIRS) {
            const float2 v = reinterpret_cast<const float2*>(lw)[i];
            lwh[i] = __builtin_amdgcn_cvt_pkrtz(v.x, v.y);
        } else {
            const float2 v = reinterpret_cast<const float2*>(fw)[i - LW_PAIRS];
            fwh[i - LW_PAIRS] = __builtin_amdgcn_cvt_pkrtz(v.x, v.y);
        }
    }

    const int row = blockIdx.x >> 1;
    const float* __restrict__ xr = x + (size_t)row * SIGLEN;
    __fp16* __restrict__ pr = pooled + (size_t)row * COMB;
    if (blockIdx.x & 1) dwt_body<1>(xr, pr, A, Bb, D1, D2, tid);
    else                dwt_body<0>(xr, pr, A, Bb, D1, D2, tid);
}

// ---------------- MLP (f16 pooled input, pre-packed f16 weights) ----------------

__global__ __launch_bounds__(1024, 4) void mlp_kernel(const __fp16* __restrict__ pooled,
                                                      const h2* __restrict__ lwh,
                                                      const float* __restrict__ lb,
                                                      const h2* __restrict__ fwh,
                                                      const float* __restrict__ fb,
                                                      float* __restrict__ out) {
    __shared__ h2 sph[8][COMB / 2];
    __shared__ h2 sch[8][COMB / 2];
    const int tid = threadIdx.x;
    const int r0 = blockIdx.x * 8;

    const h2* __restrict__ srcp = reinterpret_cast<const h2*>(pooled + (size_t)r0 * COMB);
    for (int i = tid; i < 8 * (COMB / 2); i += 1024) {
        (&sph[0][0])[i] = srcp[i];
    }
    __syncthreads();

    for (int idx = tid; idx < COMB * 2; idx += 1024) {
        const int c = idx >> 1, rh = (idx & 1) * 4;
        const h2* __restrict__ w = lwh + (size_t)c * 64;
        const int lb2 = (c >> 7) * 64;
        const float bias = lb[c];
        float acc[4] = {bias, bias, bias, bias};
        for (int t2 = 0; t2 < 64; t2 += 4) {
            const float4 wraw = *reinterpret_cast<const float4*>(w + t2);
            const h2 w0 = __builtin_bit_cast(h2, wraw.x);
            const h2 w1 = __builtin_bit_cast(h2, wraw.y);
            const h2 w2 = __builtin_bit_cast(h2, wraw.z);
            const h2 w3 = __builtin_bit_cast(h2, wraw.w);
#pragma unroll
            for (int r = 0; r < 4; ++r) {
                const float4 praw = *reinterpret_cast<const float4*>(&sph[rh + r][lb2 + t2]);
                acc[r] = __builtin_amdgcn_fdot2(__builtin_bit_cast(h2, praw.x), w0, acc[r], false);
                acc[r] = __builtin_amdgcn_fdot2(__builtin_bit_cast(h2, praw.y), w1, acc[r], false);
                acc[r] = __builtin_amdgcn_fdot2(__builtin_bit_cast(h2, praw.z), w2, acc[r], false);
                acc[r] = __builtin_amdgcn_fdot2(__builtin_bit_cast(h2, praw.w), w3, acc[r], false);
            }
        }
        __fp16* __restrict__ schf = reinterpret_cast<__fp16*>(&sch[0][0]);
#pragma unroll
        for (int r = 0; r < 4; ++r) schf[(rh + r) * COMB + c] = (__fp16)fmaxf(acc[r], 0.f);
    }
    __syncthreads();

    {
        const int c = tid >> 1, rh = (tid & 1) * 4;
        const h2* __restrict__ w = fwh + (size_t)c * (COMB / 2);
        const float bias = fb[c];
        float acc[4] = {bias, bias, bias, bias};
        for (int t2 = 0; t2 < COMB / 2; t2 += 4) {
            const float4 wraw = *reinterpret_cast<const float4*>(w + t2);
            const h2 w0 = __builtin_bit_cast(h2, wraw.x);
            const h2 w1 = __builtin_bit_cast(h2, wraw.y);
            const h2 w2 = __builtin_bit_cast(h2, wraw.z);
            const h2 w3 = __builtin_bit_cast(h2, wraw.w);
#pragma unroll
            for (int r = 0; r < 4; ++r) {
                const float4 craw = *reinterpret_cast<const float4*>(&sch[rh + r][t2]);
                acc[r] = __builtin_amdgcn_fdot2(__builtin_bit_cast(h2, craw.x), w0, acc[r], false);
                acc[r] = __builtin_amdgcn_fdot2(__builtin_bit_cast(h2, craw.y), w1, acc[r], false);
                acc[r] = __builtin_amdgcn_fdot2(__builtin_bit_cast(h2, craw.z), w2, acc[r], false);
                acc[r] = __builtin_amdgcn_fdot2(__builtin_bit_cast(h2, craw.w), w3, acc[r], false);
            }
        }
#pragma unroll
        for (int r = 0; r < 4; ++r) {
            out[(size_t)(r0 + rh + r) * OUTD + c] = fmaxf(acc[r], 0.f);
        }
    }
}

// Fallback mlp: in-kernel weight cvt (used if d_ws lacks packed-weight space)
__global__ __launch_bounds__(512) void mlp_kernel_fb(const __fp16* __restrict__ pooled,
                                                     const float* __restrict__ lw,
                                                     const float* __restrict__ lb,
                                                     const float* __restrict__ fw,
                                                     const float* __restrict__ fb,
                                                     float* __restrict__ out) {
    __shared__ h2 sph[8][COMB / 2];
    __shared__ h2 sch[8][COMB / 2];
    const int tid = threadIdx.x;
    const int r0 = blockIdx.x * 8;
    const h2* __restrict__ srcp = reinterpret_cast<const h2*>(pooled + (size_t)r0 * COMB);
    for (int i = tid; i < 8 * (COMB / 2); i += 512) {
        (&sph[0][0])[i] = srcp[i];
    }
    __syncthreads();
    for (int c = tid; c < COMB; c += 512) {
        const float* __restrict__ w = lw + (size_t)c * POOLP;
        const int lb2 = (c >> 7) * (POOLP / 2);
        const float bias = lb[c];
        float acc[8];
#pragma unroll
    for (int r = 0; r < 8; ++r) acc[r] = bias;
        for (int t2 = 0; t2 < POOLP / 2; t2 += 4) {
            const float4 wa = *reinterpret_cast<const float4*>(w + t2 * 2);
            const float4 wb = *reinterpret_cast<const float4*>(w + t2 * 2 + 4);
            const h2 w0 = __builtin_amdgcn_cvt_pkrtz(wa.x, wa.y);
            const h2 w1 = __builtin_amdgcn_cvt_pkrtz(wa.z, wa.w);
            const h2 w2 = __builtin_amdgcn_cvt_pkrtz(wb.x, wb.y);
            const h2 w3 = __builtin_amdgcn_cvt_pkrtz(wb.z, wb.w);
#pragma unroll
            for (int r = 0; r < 8; ++r) {
                const float4 raw = *reinterpret_cast<const float4*>(&sph[r][lb2 + t2]);
                acc[r] = __builtin_amdgcn_fdot2(__builtin_bit_cast(h2, raw.x), w0, acc[r], false);
                acc[r] = __builtin_amdgcn_fdot2(__builtin_bit_cast(h2, raw.y), w1, acc[r], false);
                acc[r] = __builtin_amdgcn_fdot2(__builtin_bit_cast(h2, raw.z), w2, acc[r], false);
                acc[r] = __builtin_amdgcn_fdot2(__builtin_bit_cast(h2, raw.w), w3, acc[r], false);
            }
        }
        __fp16* __restrict__ schf = reinterpret_cast<__fp16*>(&sch[0][0]);
#pragma unroll
        for (int r = 0; r < 8; ++r) schf[r * COMB + c] = (__fp16)fmaxf(acc[r], 0.f);
    }
    __syncthreads();
    {
        const int j = tid;
        const float* __restrict__ w = fw + (size_t)j * COMB;
        const float bias = fb[j];
        float acc[8];
#pragma unroll
        for (int r = 0; r < 8; ++r) acc[r] = bias;
        for (int t2 = 0; t2 < COMB / 2; t2 += 4) {
            const float4 wa = *reinterpret_cast<const float4*>(w + t2 * 2);
            const float4 wb = *reinterpret_cast<const float4*>(w + t2 * 2 + 4);
            const h2 w0 = __builtin_amdgcn_cvt_pkrtz(wa.x, wa.y);
            const h2 w1 = __builtin_amdgcn_cvt_pkrtz(wa.z, wa.w);
            const h2 w2 = __builtin_amdgcn_cvt_pkrtz(wb.x, wb.y);
            const h2 w3 = __builtin_amdgcn_cvt_pkrtz(wb.z, wb.w);
#pragma unroll
            for (int r = 0; r < 8; ++r) {
                const float4 raw = *reinterpret_cast<const float4*>(&sch[r][t2]);
                acc[r] = __builtin_amdgcn_fdot2(__builtin_bit_cast(h2, raw.x), w0, acc[r], false);
                acc[r] = __builtin_amdgcn_fdot2(__builtin_bit_cast(h2, raw.y), w1, acc[r], false);
                acc[r] = __builtin_amdgcn_fdot2(__builtin_bit_cast(h2, raw.z), w2, acc[r], false);
                acc[r] = __builtin_amdgcn_fdot2(__builtin_bit_cast(h2, raw.w), w3, acc[r], false);
            }
        }
#pragma unroll
        for (int r = 0; r < 8; ++r) {
            out[(size_t)(r0 + r) * OUTD + j] = fmaxf(acc[r], 0.f);
        }
    }
}

extern "C" void kernel_launch(void* const* d_in, const int* in_sizes, int n_in,
                              void* d_out, int out_size, void* d_ws, size_t ws_size,
                              hipStream_t stream) {
    const float* x  = (const float*)d_in[0];
    const float* lw = (const float*)d_in[1];
    const float* lb = (const float*)d_in[2];
    const float* fw = (const float*)d_in[3];
    const float* fb = (const float*)d_in[4];
    float* out = (float*)d_out;

    char* base = (char*)d_ws;
    const size_t POOLED_B = (size_t)BATCH * COMB * 2;            // f16, 2,621,440
    const size_t LWH_B    = (size_t)LW_PAIRS * 4;                // 163,840
    const size_t FWH_B    = (size_t)FW_PAIRS * 4;                // 655,360

    __fp16* pooled = (__fp16*)base;
    h2* lwh = (h2*)(base + POOLED_B);
    h2* fwh = (h2*)(base + POOLED_B + LWH_B);

    const bool packed = (ws_size >= POOLED_B + LWH_B + FWH_B);

    dwt_pool_kernel<<<BATCH * 2, NTHR, 0, stream>>>(x, pooled, lw, fw,
                                                    packed ? lwh : nullptr,
                                                    packed ? fwh : nullptr);

    if (packed) {
        mlp_kernel<<<BATCH / 8, 1024, 0, stream>>>(pooled, lwh, lb, fwh, fb, out);
    } else {
        mlp_kernel_fb<<<BATCH / 8, 512, 0, stream>>>(pooled, lw, lb, fw, fb, out);
    }
}